// Round 3
// baseline (172.686 us; speedup 1.0000x reference)
//
#include <hip/hip_runtime.h>
#include <hip/hip_bf16.h>
#include <stdint.h>

// BLSTMCell: gates = [x|hx] @ sign([W_ih|W_hh])^T + (b_ih+b_hh); LSTM pointwise.
// M=8192, N=2048 (4 gates x 512 cols), K=1024.
// int16 fixed point (scale 2^12) split into hi/lo int8; two i8 MFMA passes,
// exact i32 accumulation: gates = hi*2^-4 + lo*2^-12 + bias.
// R9: BARRIER-FREE K-loop. B panel (8 groups x 16KB) staged to LDS once in two
// 64KB halves (3 lgkm-only barriers total); after staging LDS is read-only.
// A (Xhi/Xlo) read direct from L2 as MFMA fragments (FETCH_SIZE confirmed
// L2-resident in R8), depth-1 parity prefetch. Wave tile 64x64 (32 MFMA/step,
// acc 128 regs -> AGPRs); block 512thr = 4Mx2N waves, tile 256x128, grid 512.
// Bijective XCD swizzle: XCD x owns row-tiles 4x..4x+3 -> <=1MB A live + 2MB B
// in its 4MB L2. s_setprio around MFMA cluster (waves drift into distinct
// phases -> scheduler has roles to arbitrate).
// ws: Xhi int8[8192x1024] (8MB) | Xlo (8MB) | Bp int8[2048x1024] (2MB).

typedef __attribute__((ext_vector_type(4))) int int4x;
typedef __attribute__((ext_vector_type(4))) float float4x;

#define B_DIM 8192
#define H_DIM 512

__device__ __forceinline__ float bf2f(uint16_t u) {
  return __uint_as_float(((uint32_t)u) << 16);
}
__device__ __forceinline__ uint16_t f2bf(float f) {
  uint32_t u = __float_as_uint(f);
  return (uint16_t)((u + 0x7FFFu + ((u >> 16) & 1u)) >> 16);
}
__device__ __forceinline__ float sigm(float x) { return 1.0f / (1.0f + __expf(-x)); }
__device__ __forceinline__ float tanh_f(float x) { return 2.0f / (1.0f + __expf(-2.0f * x)) - 1.0f; }

// fp32 buffers: low halves of dwords as bf16 have ~uniform exponents -> huge.
// genuine bf16 N(0,1)/uniform never exceeds 2^6. Wave-uniform result.
__device__ __forceinline__ int detect_f32(const void* x) {
  const int l = threadIdx.x & 63;
  uint32_t wrd = ((const uint32_t*)x)[l];
  uint32_t e0 = (wrd >> 7) & 0xFFu, e1 = (wrd >> 23) & 0xFFu;
  return __ballot(e0 > 0x85u || e1 > 0x85u) != 0ull;
}

__device__ __forceinline__ void quant4(const float* v, uint32_t* hi4, uint32_t* lo4) {
  uint32_t h = 0, lo = 0;
#pragma unroll
  for (int j = 0; j < 4; ++j) {
    float c = fminf(fmaxf(v[j], -8.0f), 8.0f);
    int xf = __float2int_rn(c * 4096.0f);
    xf = xf > 32639 ? 32639 : xf;
    xf = xf < -32768 ? -32768 : xf;
    const int lb = (xf << 24) >> 24;   // sign-extended low byte
    const int hb = (xf - lb) >> 8;     // exact: xf = hb*256 + lb
    lo |= ((uint32_t)lb & 0xFFu) << (8 * j);
    h |= ((uint32_t)hb & 0xFFu) << (8 * j);
  }
  *hi4 = h;
  *lo4 = lo;
}

// ---------------- prep: 3-phase LDS transpose, coalesced both sides ----------------
// Fragment tile layout (1KB = 16 rows x 64 k): byte = quad*256 + row*16 + (k&15),
// quad = (k>>4)&3, tile index = rowgroup*16 + (k>>6).
__global__ __launch_bounds__(256) void prep_kernel(
    const void* __restrict__ x, const void* __restrict__ hx,
    const void* __restrict__ w_ih, const void* __restrict__ w_hh,
    int8_t* __restrict__ Xhi, int8_t* __restrict__ Xlo, int8_t* __restrict__ Bp) {
  __shared__ alignas(16) char lsc[33280];  // hi [0,16640), lo [16640,33280)
  const int isF32 = detect_f32(x);
  const int t = threadIdx.x;
  const int w = t >> 6, l = t & 63;
  const int isX = blockIdx.x < 512;
  const int grp = isX ? blockIdx.x : (blockIdx.x - 512);  // mgroup or pgroup

#pragma unroll
  for (int rr = 0; rr < 4; ++rr) {
    const int r = w * 4 + rr;
    long rowbase;
    if (isX) rowbase = (long)(grp * 16 + r) * 512;
    else     rowbase = (long)((grp & 3) * 512 + (grp >> 2) * 16 + r) * 512;
#pragma unroll
    for (int src = 0; src < 2; ++src) {
      const void* sp_ = isX ? (src ? hx : x) : (src ? w_hh : w_ih);
#pragma unroll
      for (int q = 0; q < 2; ++q) {
        const int k = src * 512 + q * 256 + l * 4;  // global k of 4 elems
        float v[4];
        if (isF32) {
          float4x f = *(const float4x*)((const float*)sp_ + rowbase + q * 256 + l * 4);
          v[0] = f[0]; v[1] = f[1]; v[2] = f[2]; v[3] = f[3];
        } else {
          const uint16_t* s = (const uint16_t*)sp_ + rowbase + q * 256 + l * 4;
#pragma unroll
          for (int j = 0; j < 4; ++j) v[j] = bf2f(s[j]);
        }
        if (isX) {
          uint32_t h4, lo4;
          quant4(v, &h4, &lo4);
          *(uint32_t*)(lsc + r * 1040 + k) = h4;
          *(uint32_t*)(lsc + 16640 + r * 1040 + k) = lo4;
        } else {
          uint32_t s4 = 0;
#pragma unroll
          for (int j = 0; j < 4; ++j) {
            const int sv = v[j] > 0.f ? 1 : (v[j] < 0.f ? -1 : 0);
            s4 |= ((uint32_t)sv & 0xFFu) << (8 * j);
          }
          *(uint32_t*)(lsc + r * 1040 + k) = s4;
        }
      }
    }
  }
  __syncthreads();
  const int kt = t >> 4, quad = (t >> 2) & 3, rb = (t & 3) * 4;
  const int loff = kt * 64 + quad * 16;
  if (isX) {
    int4x h[4], lo[4];
#pragma unroll
    for (int i = 0; i < 4; ++i) {
      h[i] = *(const int4x*)(lsc + (rb + i) * 1040 + loff);
      lo[i] = *(const int4x*)(lsc + 16640 + (rb + i) * 1040 + loff);
    }
    int4x* dh = (int4x*)(Xhi + (long)grp * 16384 + t * 64);
    int4x* dl = (int4x*)(Xlo + (long)grp * 16384 + t * 64);
#pragma unroll
    for (int i = 0; i < 4; ++i) { dh[i] = h[i]; dl[i] = lo[i]; }
  } else {
    int4x s[4];
#pragma unroll
    for (int i = 0; i < 4; ++i)
      s[i] = *(const int4x*)(lsc + (rb + i) * 1040 + loff);
    int4x* db = (int4x*)(Bp + (long)grp * 16384 + t * 64);
#pragma unroll
    for (int i = 0; i < 4; ++i) db[i] = s[i];
  }
}

// ---------- fused GEMM: barrier-free K-loop, B-in-LDS (once), A-direct L2 ----------
// 512 blocks x 512 threads (8 waves as 4M x 2N; wave tile 64x64).
// LDS 64KB holds half the B panel (8 groups x 8KB, K-half 512); restaged once at
// ks==8 with lgkm-only barriers. Per K-step per wave: 8 global_load_dwordx4
// (A hi/lo prefetch), 4 ds_read_b128 (B frags), 32 MFMA. No per-step barriers.
__global__ __launch_bounds__(512, 2) void blstm_gemm_kernel(
    const int8_t* __restrict__ Xhi, const int8_t* __restrict__ Xlo,
    const int8_t* __restrict__ Bp, const void* __restrict__ b_ih,
    const void* __restrict__ b_hh, const void* __restrict__ cx,
    const void* __restrict__ xdet, void* __restrict__ out) {
  __shared__ alignas(16) char lds[65536];  // B half-panel: 8 groups x 8KB
  const int tid = threadIdx.x;
  const int l = tid & 63, w = tid >> 6;
  const int lrow = l & 15, lq = l >> 4;
  const int wy = w >> 1, wx = w & 1;  // 4 row-waves x 2 col-waves
  const int isF32 = detect_f32(xdet);
  const int bid = blockIdx.x;
  // Bijective XCD swizzle (hw xcd = bid%8): XCD x hosts row-tiles 4x..4x+3.
  // Live working set per XCD: <=2 row-tiles A (1MB hi+lo) + full B (2MB) < 4MB L2.
  const int rt = (bid & 7) * 4 + (bid >> 7);  // row-tile [0,32), 256 rows
  const int bx = (bid >> 3) & 15;             // col-panel [0,16), 32 cols/gate

  // A fragment pointers (prep wrote exact frag layout: 16KB tiles of 16 rows,
  // 1KB per k-step, lane l owns bytes [l*16, l*16+16)).
  const int8_t* aph[4];
  const int8_t* apl[4];
#pragma unroll
  for (int mt = 0; mt < 4; ++mt) {
    const long off = ((long)(rt * 16 + wy * 4 + mt) << 14) + l * 16;
    aph[mt] = Xhi + off;
    apl[mt] = Xlo + off;
  }
  const int8_t* bsrc = Bp + ((long)(bx * 8) << 14) + tid * 16;  // 8 groups, halves

  int4x acch[4][4], accl[4][4];
#pragma unroll
  for (int mt = 0; mt < 4; ++mt)
#pragma unroll
    for (int g = 0; g < 4; ++g) {
      acch[mt][g] = (int4x){0, 0, 0, 0};
      accl[mt][g] = (int4x){0, 0, 0, 0};
    }

  // Issue A loads for ks=0 first; they fly while B half 0 stages.
  int4x ah[2][4], al[2][4];
#pragma unroll
  for (int mt = 0; mt < 4; ++mt) {
    ah[0][mt] = *(const int4x*)aph[mt]; aph[mt] += 1024;
    al[0][mt] = *(const int4x*)apl[mt]; apl[mt] += 1024;
  }
  // Stage B half 0: group g chunk-range [0,8) -> lds[g*8192 + tid*16].
#pragma unroll
  for (int g = 0; g < 8; ++g)
    *(int4x*)(lds + g * 8192 + tid * 16) = *(const int4x*)(bsrc + g * 16384);
  asm volatile("s_waitcnt lgkmcnt(0)\n\ts_barrier" ::: "memory");

#pragma unroll
  for (int ks = 0; ks < 16; ++ks) {
    const int cur = ks & 1, nxt = cur ^ 1;
    if (ks == 8) {
      // barrier 1: all waves have consumed their half-0 ds_reads (MFMA deps
      // forced lgkm drain); safe to overwrite. A loads stay in flight (lgkm-only).
      asm volatile("s_waitcnt lgkmcnt(0)\n\ts_barrier" ::: "memory");
#pragma unroll
      for (int g = 0; g < 8; ++g)
        *(int4x*)(lds + g * 8192 + tid * 16) = *(const int4x*)(bsrc + g * 16384 + 8192);
      asm volatile("s_waitcnt lgkmcnt(0)\n\ts_barrier" ::: "memory");
    }
    if (ks < 15) {  // depth-1 A prefetch: ~1 full step (>=300cy) of slack vs ~200cy L2
#pragma unroll
      for (int mt = 0; mt < 4; ++mt) {
        ah[nxt][mt] = *(const int4x*)aph[mt]; aph[mt] += 1024;
        al[nxt][mt] = *(const int4x*)apl[mt]; apl[mt] += 1024;
      }
    }
    int4x b[4];
#pragma unroll
    for (int g = 0; g < 4; ++g)
      b[g] = *(const int4x*)(lds + (wx * 4 + g) * 8192 + (ks & 7) * 1024 + l * 16);
    __builtin_amdgcn_s_setprio(1);
#pragma unroll
    for (int mt = 0; mt < 4; ++mt)
#pragma unroll
      for (int g = 0; g < 4; ++g) {
        acch[mt][g] = __builtin_amdgcn_mfma_i32_16x16x64_i8(ah[cur][mt], b[g], acch[mt][g], 0, 0, 0);
        accl[mt][g] = __builtin_amdgcn_mfma_i32_16x16x64_i8(al[cur][mt], b[g], accl[mt][g], 0, 0, 0);
      }
    __builtin_amdgcn_s_setprio(0);
  }

  // ---------------- epilogue: per-lane, all 4 gates in-register ---------------------
  const long CYo = (long)B_DIM * H_DIM;
  const int c = bx * 32 + wx * 16 + lrow;  // h-column of this lane
  float biasv[4];
#pragma unroll
  for (int g = 0; g < 4; ++g) {
    if (isF32)
      biasv[g] = ((const float*)b_ih)[g * 512 + c] + ((const float*)b_hh)[g * 512 + c];
    else
      biasv[g] = bf2f(((const uint16_t*)b_ih)[g * 512 + c]) + bf2f(((const uint16_t*)b_hh)[g * 512 + c]);
  }
  float* outF = (float*)out;
  uint16_t* outB = (uint16_t*)out;
#pragma unroll
  for (int mt = 0; mt < 4; ++mt) {
#pragma unroll
    for (int r = 0; r < 4; ++r) {
      const int row = rt * 256 + wy * 64 + mt * 16 + lq * 4 + r;
      const long cidx = (long)row * H_DIM + c;
      float vg[4];
#pragma unroll
      for (int g = 0; g < 4; ++g)
        vg[g] = fmaf((float)acch[mt][g][r], 0.0625f,
                     fmaf((float)accl[mt][g][r], 2.44140625e-4f, biasv[g]));
      const float cxv = isF32 ? ((const float*)cx)[cidx] : bf2f(((const uint16_t*)cx)[cidx]);
      const float ig = sigm(vg[0]), fg = sigm(vg[1]), og = sigm(vg[3]);
      const float cg = tanh_f(vg[2]);
      const float cy = fg * cxv + ig * cg;
      const float hy = og * tanh_f(cy);
      if (isF32) {
        outF[cidx] = hy;
        outF[CYo + cidx] = cy;
      } else {
        outB[cidx] = f2bf(hy);
        outB[CYo + cidx] = f2bf(cy);
      }
    }
  }
}

extern "C" void kernel_launch(void* const* d_in, const int* in_sizes, int n_in,
                              void* d_out, int out_size, void* d_ws, size_t ws_size,
                              hipStream_t stream) {
  const void* x = d_in[0];
  const void* hx = d_in[1];
  const void* cx = d_in[2];
  const void* W_ih = d_in[3];
  const void* W_hh = d_in[4];
  const void* b_ih = d_in[5];
  const void* b_hh = d_in[6];
  char* ws = (char*)d_ws;
  int8_t* Xhi = (int8_t*)ws;                   // 8 MB
  int8_t* Xlo = (int8_t*)(ws + 8388608);       // 8 MB
  int8_t* Bp = (int8_t*)(ws + 16777216);       // 2 MB

  prep_kernel<<<640, 256, 0, stream>>>(x, hx, W_ih, W_hh, Xhi, Xlo, Bp);
  blstm_gemm_kernel<<<512, 512, 0, stream>>>(Xhi, Xlo, Bp, b_ih, b_hh, cx, x, d_out);
}

// Round 4
// 151.931 us; speedup vs baseline: 1.1366x; 1.1366x over previous
//
#include <hip/hip_runtime.h>
#include <hip/hip_bf16.h>
#include <stdint.h>

// BLSTMCell: gates = [x|hx] @ sign([W_ih|W_hh])^T + (b_ih+b_hh); LSTM pointwise.
// M=8192, N=2048 (4 gates x 512 cols), K=1024.
// int16 fixed point (scale 2^12) split into hi/lo int8; two i8 MFMA passes,
// exact i32 accumulation: gates = hi*2^-4 + lo*2^-12 + bias.
// R10: back to full-LDS staging (A-direct refuted: R8/R9 regressions — global
// latency at shallow depth beats LDS cost). R7 was LDS-BW-bound (352KB/CU-step
// vs 2600cy MFMA). Fix: (1) wave tile 64x64 -> 375 B LDS-read per MFMA,
// (2) global_load_lds staging (no VGPR round-trip / ds_write pipe),
// (3) TRIPLE-buffered LDS + counted vmcnt(6) per step (T3/T4): stage tile
// ks+2 after the barrier, end step with vmcnt(6)+lgkm(0)+s_barrier — loads
// never drain in-loop. Block 4 waves (2x2), tile 128x128, grid 1024,
// 72KB LDS -> 2 blocks/CU. XCD swizzle, bx-fastest (A panel L2-reused 16x).
// ws: Xhi int8[8192x1024] (8MB) | Xlo (8MB) | Bp int8[2048x1024] (2MB).

typedef __attribute__((ext_vector_type(4))) int int4x;
typedef __attribute__((ext_vector_type(4))) float float4x;

#define B_DIM 8192
#define H_DIM 512

__device__ __forceinline__ float bf2f(uint16_t u) {
  return __uint_as_float(((uint32_t)u) << 16);
}
__device__ __forceinline__ uint16_t f2bf(float f) {
  uint32_t u = __float_as_uint(f);
  return (uint16_t)((u + 0x7FFFu + ((u >> 16) & 1u)) >> 16);
}
__device__ __forceinline__ float sigm(float x) { return 1.0f / (1.0f + __expf(-x)); }
__device__ __forceinline__ float tanh_f(float x) { return 2.0f / (1.0f + __expf(-2.0f * x)) - 1.0f; }

// fp32 buffers: low halves of dwords as bf16 have ~uniform exponents -> huge.
// genuine bf16 N(0,1)/uniform never exceeds 2^6. Wave-uniform result.
__device__ __forceinline__ int detect_f32(const void* x) {
  const int l = threadIdx.x & 63;
  uint32_t wrd = ((const uint32_t*)x)[l];
  uint32_t e0 = (wrd >> 7) & 0xFFu, e1 = (wrd >> 23) & 0xFFu;
  return __ballot(e0 > 0x85u || e1 > 0x85u) != 0ull;
}

__device__ __forceinline__ void quant4(const float* v, uint32_t* hi4, uint32_t* lo4) {
  uint32_t h = 0, lo = 0;
#pragma unroll
  for (int j = 0; j < 4; ++j) {
    float c = fminf(fmaxf(v[j], -8.0f), 8.0f);
    int xf = __float2int_rn(c * 4096.0f);
    xf = xf > 32639 ? 32639 : xf;
    xf = xf < -32768 ? -32768 : xf;
    const int lb = (xf << 24) >> 24;   // sign-extended low byte
    const int hb = (xf - lb) >> 8;     // exact: xf = hb*256 + lb
    lo |= ((uint32_t)lb & 0xFFu) << (8 * j);
    h |= ((uint32_t)hb & 0xFFu) << (8 * j);
  }
  *hi4 = h;
  *lo4 = lo;
}

// async global->LDS, 16B per lane; LDS dest is wave-uniform base + lane*16.
__device__ __forceinline__ void gload16(const void* g, void* l) {
  __builtin_amdgcn_global_load_lds(
      (const __attribute__((address_space(1))) unsigned int*)g,
      (__attribute__((address_space(3))) unsigned int*)l, 16, 0, 0);
}

// ---------------- prep: 3-phase LDS transpose, coalesced both sides ----------------
// Fragment tile layout (1KB = 16 rows x 64 k): byte = quad*256 + row*16 + (k&15),
// quad = (k>>4)&3, tile index = rowgroup*16 + (k>>6).
__global__ __launch_bounds__(256) void prep_kernel(
    const void* __restrict__ x, const void* __restrict__ hx,
    const void* __restrict__ w_ih, const void* __restrict__ w_hh,
    int8_t* __restrict__ Xhi, int8_t* __restrict__ Xlo, int8_t* __restrict__ Bp) {
  __shared__ alignas(16) char lsc[33280];  // hi [0,16640), lo [16640,33280)
  const int isF32 = detect_f32(x);
  const int t = threadIdx.x;
  const int w = t >> 6, l = t & 63;
  const int isX = blockIdx.x < 512;
  const int grp = isX ? blockIdx.x : (blockIdx.x - 512);  // mgroup or pgroup

#pragma unroll
  for (int rr = 0; rr < 4; ++rr) {
    const int r = w * 4 + rr;
    long rowbase;
    if (isX) rowbase = (long)(grp * 16 + r) * 512;
    else     rowbase = (long)((grp & 3) * 512 + (grp >> 2) * 16 + r) * 512;
#pragma unroll
    for (int src = 0; src < 2; ++src) {
      const void* sp_ = isX ? (src ? hx : x) : (src ? w_hh : w_ih);
#pragma unroll
      for (int q = 0; q < 2; ++q) {
        const int k = src * 512 + q * 256 + l * 4;  // global k of 4 elems
        float v[4];
        if (isF32) {
          float4x f = *(const float4x*)((const float*)sp_ + rowbase + q * 256 + l * 4);
          v[0] = f[0]; v[1] = f[1]; v[2] = f[2]; v[3] = f[3];
        } else {
          const uint16_t* s = (const uint16_t*)sp_ + rowbase + q * 256 + l * 4;
#pragma unroll
          for (int j = 0; j < 4; ++j) v[j] = bf2f(s[j]);
        }
        if (isX) {
          uint32_t h4, lo4;
          quant4(v, &h4, &lo4);
          *(uint32_t*)(lsc + r * 1040 + k) = h4;
          *(uint32_t*)(lsc + 16640 + r * 1040 + k) = lo4;
        } else {
          uint32_t s4 = 0;
#pragma unroll
          for (int j = 0; j < 4; ++j) {
            const int sv = v[j] > 0.f ? 1 : (v[j] < 0.f ? -1 : 0);
            s4 |= ((uint32_t)sv & 0xFFu) << (8 * j);
          }
          *(uint32_t*)(lsc + r * 1040 + k) = s4;
        }
      }
    }
  }
  __syncthreads();
  const int kt = t >> 4, quad = (t >> 2) & 3, rb = (t & 3) * 4;
  const int loff = kt * 64 + quad * 16;
  if (isX) {
    int4x h[4], lo[4];
#pragma unroll
    for (int i = 0; i < 4; ++i) {
      h[i] = *(const int4x*)(lsc + (rb + i) * 1040 + loff);
      lo[i] = *(const int4x*)(lsc + 16640 + (rb + i) * 1040 + loff);
    }
    int4x* dh = (int4x*)(Xhi + (long)grp * 16384 + t * 64);
    int4x* dl = (int4x*)(Xlo + (long)grp * 16384 + t * 64);
#pragma unroll
    for (int i = 0; i < 4; ++i) { dh[i] = h[i]; dl[i] = lo[i]; }
  } else {
    int4x s[4];
#pragma unroll
    for (int i = 0; i < 4; ++i)
      s[i] = *(const int4x*)(lsc + (rb + i) * 1040 + loff);
    int4x* db = (int4x*)(Bp + (long)grp * 16384 + t * 64);
#pragma unroll
    for (int i = 0; i < 4; ++i) db[i] = s[i];
  }
}

// ------- fused GEMM: gload_lds triple-buffer, counted vmcnt, 64x64 wave tile ------
// 1024 blocks x 256 threads (4 waves as 2M x 2N; wave tile 64x64, 32 MFMA/step).
// LDS buffer (24KB): Ahi [0,8K) Alo [8K,16K) B [16K,24K); 3 buffers = 72KB.
// Per step: stage tile ks+2 (6 gload16/wave), 12 ds_read_b128, 32 MFMA,
// then vmcnt(6)+lgkm(0)+s_barrier (counted — loads stay in flight).
__global__ __launch_bounds__(256, 2) void blstm_gemm_kernel(
    const int8_t* __restrict__ Xhi, const int8_t* __restrict__ Xlo,
    const int8_t* __restrict__ Bp, const void* __restrict__ b_ih,
    const void* __restrict__ b_hh, const void* __restrict__ cx,
    const void* __restrict__ xdet, void* __restrict__ out) {
  __shared__ alignas(16) char lds[73728];  // 3 x 24KB
  const int tid = threadIdx.x;
  const int l = tid & 63, w = tid >> 6;
  const int lrow = l & 15, lq = l >> 4;
  const int wy = w >> 1, wx = w & 1;  // 2 row-waves x 2 col-waves
  const int isF32 = detect_f32(xdet);
  const int bid = blockIdx.x;
  // XCD swizzle (hw xcd = bid%8), bx-fastest: XCD x sweeps 16 col-panels per
  // row-band -> A panel (256KB hi+lo) L2-reused 16x, B (2MB) resident.
  const int idx = bid >> 3;                 // 0..127
  const int by = (bid & 7) * 8 + (idx >> 4);  // 0..63 (128-row tiles)
  const int bx = idx & 15;                    // 0..15 (32 h-cols x 4 gates)

  // 24 chunks of 1KB per K-step (8 Ahi + 8 Alo + 8 B); wave stages 6.
  // Chunk source ptr includes lane offset l*16; LDS dest is wave-uniform.
  const int8_t* csrc[6];
  int cdst[6];
#pragma unroll
  for (int i = 0; i < 6; ++i) {
    const int c = w * 6 + i;
    if (c < 8) {
      csrc[i] = Xhi + (((long)(by * 8 + c)) << 14) + l * 16;
      cdst[i] = c * 1024;
    } else if (c < 16) {
      csrc[i] = Xlo + (((long)(by * 8 + (c - 8))) << 14) + l * 16;
      cdst[i] = 8192 + (c - 8) * 1024;
    } else {
      csrc[i] = Bp + (((long)(bx * 8 + (c - 16))) << 14) + l * 16;
      cdst[i] = 16384 + (c - 16) * 1024;
    }
  }

  int4x acch[4][4], accl[4][4];
#pragma unroll
  for (int mt = 0; mt < 4; ++mt)
#pragma unroll
    for (int g = 0; g < 4; ++g) {
      acch[mt][g] = (int4x){0, 0, 0, 0};
      accl[mt][g] = (int4x){0, 0, 0, 0};
    }

  // Prologue: stage tiles 0 (buf0) and 1 (buf1); wait for tile 0 only.
#pragma unroll
  for (int i = 0; i < 6; ++i) gload16(csrc[i], lds + cdst[i]);
#pragma unroll
  for (int i = 0; i < 6; ++i) gload16(csrc[i] + 1024, lds + 24576 + cdst[i]);
  asm volatile("s_waitcnt vmcnt(6)\n\ts_barrier" ::: "memory");

#pragma unroll
  for (int ks = 0; ks < 16; ++ks) {
    const int cb = (ks % 3) * 24576;  // compile-time (full unroll)
    if (ks < 14) {                    // stage tile ks+2 (safe: ks-1 readers done)
      const int nb = ((ks + 2) % 3) * 24576;
#pragma unroll
      for (int i = 0; i < 6; ++i)
        gload16(csrc[i] + (long)(ks + 2) * 1024, lds + nb + cdst[i]);
    }
    int4x ah[4], al[4], b[4];
#pragma unroll
    for (int mt = 0; mt < 4; ++mt) {
      ah[mt] = *(const int4x*)(lds + cb + (wy * 4 + mt) * 1024 + l * 16);
      al[mt] = *(const int4x*)(lds + cb + 8192 + (wy * 4 + mt) * 1024 + l * 16);
    }
#pragma unroll
    for (int g = 0; g < 4; ++g)
      b[g] = *(const int4x*)(lds + cb + 16384 + (wx * 4 + g) * 1024 + l * 16);
    __builtin_amdgcn_s_setprio(1);
#pragma unroll
    for (int mt = 0; mt < 4; ++mt)
#pragma unroll
      for (int g = 0; g < 4; ++g) {
        acch[mt][g] = __builtin_amdgcn_mfma_i32_16x16x64_i8(ah[mt], b[g], acch[mt][g], 0, 0, 0);
        accl[mt][g] = __builtin_amdgcn_mfma_i32_16x16x64_i8(al[mt], b[g], accl[mt][g], 0, 0, 0);
      }
    __builtin_amdgcn_s_setprio(0);
    // End of step: ensure tile ks+1 staged (all waves), my LDS reads done.
    // Outstanding: 6 (tile ks+1) + 6 (tile ks+2) -> vmcnt(6); at ks=14 only
    // tile 15's 6 remain -> vmcnt(0) (tail); ks=15 falls through to epilogue.
    if (ks < 14)
      asm volatile("s_waitcnt vmcnt(6)\n\ts_waitcnt lgkmcnt(0)\n\ts_barrier" ::: "memory");
    else if (ks == 14)
      asm volatile("s_waitcnt vmcnt(0)\n\ts_waitcnt lgkmcnt(0)\n\ts_barrier" ::: "memory");
  }

  // ---------------- epilogue: per-lane, all 4 gates in-register ---------------------
  const long CYo = (long)B_DIM * H_DIM;
  const int c = bx * 32 + wx * 16 + lrow;  // h-column of this lane
  float biasv[4];
#pragma unroll
  for (int g = 0; g < 4; ++g) {
    if (isF32)
      biasv[g] = ((const float*)b_ih)[g * 512 + c] + ((const float*)b_hh)[g * 512 + c];
    else
      biasv[g] = bf2f(((const uint16_t*)b_ih)[g * 512 + c]) + bf2f(((const uint16_t*)b_hh)[g * 512 + c]);
  }
  float* outF = (float*)out;
  uint16_t* outB = (uint16_t*)out;
#pragma unroll
  for (int mt = 0; mt < 4; ++mt) {
#pragma unroll
    for (int r = 0; r < 4; ++r) {
      const int row = by * 128 + wy * 64 + mt * 16 + lq * 4 + r;
      const long cidx = (long)row * H_DIM + c;
      float vg[4];
#pragma unroll
      for (int g = 0; g < 4; ++g)
        vg[g] = fmaf((float)acch[mt][g][r], 0.0625f,
                     fmaf((float)accl[mt][g][r], 2.44140625e-4f, biasv[g]));
      const float cxv = isF32 ? ((const float*)cx)[cidx] : bf2f(((const uint16_t*)cx)[cidx]);
      const float ig = sigm(vg[0]), fg = sigm(vg[1]), og = sigm(vg[3]);
      const float cg = tanh_f(vg[2]);
      const float cy = fg * cxv + ig * cg;
      const float hy = og * tanh_f(cy);
      if (isF32) {
        outF[cidx] = hy;
        outF[CYo + cidx] = cy;
      } else {
        outB[cidx] = f2bf(hy);
        outB[CYo + cidx] = f2bf(cy);
      }
    }
  }
}

extern "C" void kernel_launch(void* const* d_in, const int* in_sizes, int n_in,
                              void* d_out, int out_size, void* d_ws, size_t ws_size,
                              hipStream_t stream) {
  const void* x = d_in[0];
  const void* hx = d_in[1];
  const void* cx = d_in[2];
  const void* W_ih = d_in[3];
  const void* W_hh = d_in[4];
  const void* b_ih = d_in[5];
  const void* b_hh = d_in[6];
  char* ws = (char*)d_ws;
  int8_t* Xhi = (int8_t*)ws;                   // 8 MB
  int8_t* Xlo = (int8_t*)(ws + 8388608);       // 8 MB
  int8_t* Bp = (int8_t*)(ws + 16777216);       // 2 MB

  prep_kernel<<<640, 256, 0, stream>>>(x, hx, W_ih, W_hh, Xhi, Xlo, Bp);
  blstm_gemm_kernel<<<1024, 256, 0, stream>>>(Xhi, Xlo, Bp, b_ih, b_hh, cx, x, d_out);
}